// Round 1
// baseline (86.339 us; speedup 1.0000x reference)
//
#include <hip/hip_runtime.h>

// OversizeConv2d: separable depthwise conv, K=127, pad=63 over 64x64 images.
// Full-coverage kernel => per-channel dense 64x64 Toeplitz matmul along H then W.
// Fused single kernel: one block per (b,c) image, both passes in LDS.

#define HH  64
#define WW  64
#define KS  13
#define STR 65   // LDS row stride: 65 % 32 == 1 -> conflict-free row and column access

__global__ __launch_bounds__(256, 4)
void oversize_conv_fused(const float* __restrict__ x,
                         const float* __restrict__ hwt,   // (128,1,13,1) flat
                         const float* __restrict__ wwt,   // (128,1,1,13) flat
                         const float* __restrict__ hb,
                         const float* __restrict__ wb,
                         float* __restrict__ out)
{
    __shared__ float Xs[HH * STR];
    __shared__ float Ys[HH * STR];
    __shared__ float hk[128];
    __shared__ float wk[128];

    const int tid = threadIdx.x;
    const int bc  = blockIdx.x;        // b*128 + c
    const int c   = bc & 127;
    const size_t img = (size_t)bc * (HH * WW);

    // ---- interpolate 13 -> 127 taps (align_corners=True linear), per channel
    if (tid < 127) {
        const float scale = 12.0f / 126.0f;
        float pos  = (float)tid * scale;
        int   lo   = (int)pos;                 // pos >= 0 -> trunc == floor
        float frac = pos - (float)lo;
        int   hi   = (lo + 1 < 12) ? (lo + 1) : 12;
        hk[tid] = hwt[c * KS + lo] * (1.0f - frac) + hwt[c * KS + hi] * frac;
        wk[tid] = wwt[c * KS + lo] * (1.0f - frac) + wwt[c * KS + hi] * frac;
    }

    // ---- load X (64x64 f32) coalesced float4 -> LDS
    const float4* xg = (const float4*)(x + img);
    #pragma unroll
    for (int r = 0; r < 4; ++r) {
        int idx  = tid + r * 256;     // float4 index, 16 per row
        int row  = idx >> 4;
        int col  = (idx & 15) * 4;
        float4 v = xg[idx];
        float* d = &Xs[row * STR + col];
        d[0] = v.x; d[1] = v.y; d[2] = v.z; d[3] = v.w;
    }
    __syncthreads();

    // ---- H pass: Y[oh][w] = hb + sum_ih hk[ih-oh+63] * X[ih][w]
    // w per lane (coalesced LDS rows), oh-group wave-uniform -> hk reads broadcast.
    {
        const int w    = tid & 63;
        const int g    = __builtin_amdgcn_readfirstlane(tid >> 6);
        const int base = 63 - 16 * g;          // hk index = base + ih - i, always in [0,126]
        const float bias = hb[c];
        float acc[16];
        #pragma unroll
        for (int i = 0; i < 16; ++i) acc[i] = bias;
        #pragma unroll 16
        for (int ih = 0; ih < 64; ++ih) {
            float xv = Xs[ih * STR + w];
            #pragma unroll
            for (int i = 0; i < 16; ++i)
                acc[i] += xv * hk[base + ih - i];
        }
        #pragma unroll
        for (int i = 0; i < 16; ++i)
            Ys[(16 * g + i) * STR + w] = acc[i];
    }
    __syncthreads();

    // ---- W pass: Z[h][ow] = wb + sum_iw wk[iw-ow+63] * Y[h][iw]
    // h per lane (stride-65 rows, 65%32==1 -> conflict-free), ow-group wave-uniform.
    {
        const int h    = tid & 63;
        const int g    = __builtin_amdgcn_readfirstlane(tid >> 6);
        const int base = 63 - 16 * g;
        const float bias = wb[c];
        float acc[16];
        #pragma unroll
        for (int i = 0; i < 16; ++i) acc[i] = bias;
        #pragma unroll 16
        for (int iw = 0; iw < 64; ++iw) {
            float yv = Ys[h * STR + iw];
            #pragma unroll
            for (int i = 0; i < 16; ++i)
                acc[i] += yv * wk[base + iw - i];
        }
        #pragma unroll
        for (int i = 0; i < 16; ++i)
            Xs[h * STR + 16 * g + i] = acc[i];   // reuse Xs as Z staging
    }
    __syncthreads();

    // ---- coalesced float4 store
    #pragma unroll
    for (int r = 0; r < 4; ++r) {
        int idx = tid + r * 256;
        int row = idx >> 4;
        int col = (idx & 15) * 4;
        float4 v;
        v.x = Xs[row * STR + col + 0];
        v.y = Xs[row * STR + col + 1];
        v.z = Xs[row * STR + col + 2];
        v.w = Xs[row * STR + col + 3];
        ((float4*)(out + img))[idx] = v;
    }
}

extern "C" void kernel_launch(void* const* d_in, const int* in_sizes, int n_in,
                              void* d_out, int out_size, void* d_ws, size_t ws_size,
                              hipStream_t stream)
{
    const float* x   = (const float*)d_in[0];
    const float* hwt = (const float*)d_in[1];
    const float* wwt = (const float*)d_in[2];
    const float* hb  = (const float*)d_in[3];
    const float* wb  = (const float*)d_in[4];
    float* outp = (float*)d_out;
    const int n_img = 32 * 128;   // B * C
    oversize_conv_fused<<<n_img, 256, 0, stream>>>(x, hwt, wwt, hb, wb, outp);
}

// Round 2
// 27.573 us; speedup vs baseline: 3.1313x; 3.1313x over previous
//
#include <hip/hip_runtime.h>

// OversizeConv2d via MFMA: Z = A_h * X * A_w^T + hb*s_w[ow] + wb, per (b,c) image.
// Pass A: P = X * A_w^T   (X is A-operand, Aw stored as B^T row-major)
// Pass B: Z = A_h * P     (P written transposed to LDS by pass-A epilogue)

#define STRB 72   // bf16 LDS row stride: 144 B == 4 mod 32 banks

typedef short  bfrag  __attribute__((ext_vector_type(8)));   // 8 bf16 = 4 VGPR
typedef float  f32x4  __attribute__((ext_vector_type(4)));
typedef unsigned short us4 __attribute__((ext_vector_type(4)));

__device__ __forceinline__ unsigned short f2bf(float f) {
    unsigned u = __builtin_bit_cast(unsigned, f);
    u += 0x7fffu + ((u >> 16) & 1u);          // round-to-nearest-even
    return (unsigned short)(u >> 16);
}

__global__ __launch_bounds__(256, 4)
void oversize_conv_mfma(const float* __restrict__ x,
                        const float* __restrict__ hwt,   // (128,1,13,1)
                        const float* __restrict__ wwt,   // (128,1,1,13)
                        const float* __restrict__ hb,
                        const float* __restrict__ wb,
                        float* __restrict__ out)
{
    __shared__ __align__(16) unsigned short Xs[64 * STRB];  // X bf16, row-major [h][w]
    __shared__ __align__(16) unsigned short Aw[64 * STRB];  // B^T for pass A: Aw[ow][iw]
    __shared__ __align__(16) unsigned short Ah[64 * STRB];  // A for pass B:  Ah[oh][ih]
    __shared__ __align__(16) unsigned short PT[64 * STRB];  // P^T: PT[ow][h]
    __shared__ float hk[128], wk[128], sw[64];

    const int tid = threadIdx.x;
    const int bc  = blockIdx.x;
    const int c   = bc & 127;
    const size_t img = (size_t)bc * 4096;

    // ---- issue global X loads early (16 f32 / thread)
    float4 xv[4];
    const float4* xg = (const float4*)(x + img);
    #pragma unroll
    for (int i = 0; i < 4; ++i) xv[i] = xg[tid + i * 256];

    // ---- interpolate 13 -> 127 taps (align_corners linear), f32 in LDS
    if (tid < 127) {
        const float scale = 12.0f / 126.0f;
        float pos = (float)tid * scale;
        int   lo  = (int)pos;
        float fr  = pos - (float)lo;
        int   hi  = (lo + 1 < 12) ? lo + 1 : 12;
        hk[tid] = hwt[c * 13 + lo] * (1.0f - fr) + hwt[c * 13 + hi] * fr;
        wk[tid] = wwt[c * 13 + lo] * (1.0f - fr) + wwt[c * 13 + hi] * fr;
    }
    __syncthreads();

    // ---- build Toeplitz factors (bf16) + s_w, stage X into LDS
    {
        const int row = tid >> 2;            // 0..63
        const int cb  = (tid & 3) * 16;      // col block
        us4 vh[4], vw[4];
        #pragma unroll
        for (int q = 0; q < 4; ++q) {
            #pragma unroll
            for (int j = 0; j < 4; ++j) {
                int col = cb + q * 4 + j;                 // = ih (or iw)
                vh[q][j] = f2bf(hk[col - row + 63]);      // Ah[row=oh][col=ih]
                vw[q][j] = f2bf(wk[col - row + 63]);      // Aw[row=ow][col=iw]
            }
        }
        #pragma unroll
        for (int q = 0; q < 4; ++q) {
            *(us4*)&Ah[row * STRB + cb + q * 4] = vh[q];
            *(us4*)&Aw[row * STRB + cb + q * 4] = vw[q];
        }
    }
    if (tid < 64) {
        float s = 0.f;
        #pragma unroll 8
        for (int iw = 0; iw < 64; ++iw) s += wk[iw - tid + 63];
        sw[tid] = s;
    }
    #pragma unroll
    for (int i = 0; i < 4; ++i) {
        int idx = tid + i * 256;             // float4 index
        int row = idx >> 4;
        int col = (idx & 15) * 4;
        us4 v;
        v[0] = f2bf(xv[i].x); v[1] = f2bf(xv[i].y);
        v[2] = f2bf(xv[i].z); v[3] = f2bf(xv[i].w);
        *(us4*)&Xs[row * STRB + col] = v;
    }
    __syncthreads();

    const int wv = tid >> 6, lane = tid & 63;
    const int r = lane & 15, g = lane >> 4;

    // ---- pass A: P = X * Aw^T ; wave wv owns rows wv*16..wv*16+15
    f32x4 acc[4] = {};
    {
        bfrag a0 = *(const bfrag*)&Xs[(wv * 16 + r) * STRB + g * 8];
        bfrag a1 = *(const bfrag*)&Xs[(wv * 16 + r) * STRB + 32 + g * 8];
        #pragma unroll
        for (int nt = 0; nt < 4; ++nt) {
            bfrag b0 = *(const bfrag*)&Aw[(nt * 16 + r) * STRB + g * 8];
            bfrag b1 = *(const bfrag*)&Aw[(nt * 16 + r) * STRB + 32 + g * 8];
            acc[nt] = __builtin_amdgcn_mfma_f32_16x16x32_bf16(a0, b0, acc[nt], 0, 0, 0);
            acc[nt] = __builtin_amdgcn_mfma_f32_16x16x32_bf16(a1, b1, acc[nt], 0, 0, 0);
        }
    }
    // epilogue: write P transposed. D[row=4g+j + 16wv][col=nt*16+r] -> PT[col][row]
    #pragma unroll
    for (int nt = 0; nt < 4; ++nt) {
        us4 p;
        p[0] = f2bf(acc[nt][0]); p[1] = f2bf(acc[nt][1]);
        p[2] = f2bf(acc[nt][2]); p[3] = f2bf(acc[nt][3]);
        *(us4*)&PT[(nt * 16 + r) * STRB + wv * 16 + g * 4] = p;
    }
    __syncthreads();

    // ---- pass B: Z = A_h * P + bias
    const float hbc = hb[c], wbc = wb[c];
    f32x4 acc2[4];
    #pragma unroll
    for (int nt = 0; nt < 4; ++nt) {
        float bv = hbc * sw[nt * 16 + r] + wbc;   // col = nt*16+r
        acc2[nt] = (f32x4){bv, bv, bv, bv};
    }
    {
        bfrag a0 = *(const bfrag*)&Ah[(wv * 16 + r) * STRB + g * 8];
        bfrag a1 = *(const bfrag*)&Ah[(wv * 16 + r) * STRB + 32 + g * 8];
        #pragma unroll
        for (int nt = 0; nt < 4; ++nt) {
            bfrag b0 = *(const bfrag*)&PT[(nt * 16 + r) * STRB + g * 8];
            bfrag b1 = *(const bfrag*)&PT[(nt * 16 + r) * STRB + 32 + g * 8];
            acc2[nt] = __builtin_amdgcn_mfma_f32_16x16x32_bf16(a0, b0, acc2[nt], 0, 0, 0);
            acc2[nt] = __builtin_amdgcn_mfma_f32_16x16x32_bf16(a1, b1, acc2[nt], 0, 0, 0);
        }
    }
    // ---- store Z: D[row=16wv+4g+j][col=nt*16+r]
    float* og = out + img;
    #pragma unroll
    for (int nt = 0; nt < 4; ++nt) {
        #pragma unroll
        for (int j = 0; j < 4; ++j)
            og[(size_t)(wv * 16 + g * 4 + j) * 64 + nt * 16 + r] = acc2[nt][j];
    }
}

extern "C" void kernel_launch(void* const* d_in, const int* in_sizes, int n_in,
                              void* d_out, int out_size, void* d_ws, size_t ws_size,
                              hipStream_t stream)
{
    const float* x   = (const float*)d_in[0];
    const float* hwt = (const float*)d_in[1];
    const float* wwt = (const float*)d_in[2];
    const float* hb  = (const float*)d_in[3];
    const float* wb  = (const float*)d_in[4];
    oversize_conv_mfma<<<32 * 128, 256, 0, stream>>>(x, hwt, wwt, hb, wb, (float*)d_out);
}

// Round 3
// 25.988 us; speedup vs baseline: 3.3222x; 1.0610x over previous
//
#include <hip/hip_runtime.h>

// OversizeConv2d via MFMA: Z = A_h * X * A_w^T + hb*s_w[ow] + wb, per (b,c) image.
// Block = one channel c, 4 batch images. Toeplitz factors built once, images
// software-pipelined (prefetch regs -> LDS stage overlapped with pass B).
// Barriers are LDS-only (lgkmcnt), so global loads/stores stay in flight.

#define STRB 72   // bf16 LDS row stride: 144 B == 4 mod 32 banks

typedef short  bfrag  __attribute__((ext_vector_type(8)));   // 8 bf16 = 4 VGPR
typedef float  f32x4  __attribute__((ext_vector_type(4)));
typedef unsigned short us4 __attribute__((ext_vector_type(4)));

__device__ __forceinline__ unsigned short f2bf(float f) {
    unsigned u = __builtin_bit_cast(unsigned, f);
    u += 0x7fffu + ((u >> 16) & 1u);          // round-to-nearest-even
    return (unsigned short)(u >> 16);
}

// LDS-visibility barrier WITHOUT vmcnt drain (keeps global loads/stores in flight)
__device__ __forceinline__ void lds_barrier() {
    asm volatile("s_waitcnt lgkmcnt(0)" ::: "memory");
    __builtin_amdgcn_s_barrier();
}

__global__ __launch_bounds__(256, 4)
void oversize_conv_mfma4(const float* __restrict__ x,
                         const float* __restrict__ hwt,   // (128,1,13,1)
                         const float* __restrict__ wwt,   // (128,1,1,13)
                         const float* __restrict__ hb,
                         const float* __restrict__ wb,
                         float* __restrict__ out)
{
    __shared__ __align__(16) unsigned short Xs[64 * STRB];  // X bf16 [h][w]
    __shared__ __align__(16) unsigned short Aw[64 * STRB];  // Aw[ow][iw]  (B^T, pass A)
    __shared__ __align__(16) unsigned short Ah[64 * STRB];  // Ah[oh][ih]  (A, pass B)
    __shared__ __align__(16) unsigned short PT[64 * STRB];  // P^T [ow][h]
    __shared__ float hk[128], wk[128], sw[64];

    const int tid = threadIdx.x;
    const int c   = blockIdx.x & 127;          // channel
    const int g4  = blockIdx.x >> 7;           // batch group: batches 4*g4 .. 4*g4+3
    const size_t img0      = ((size_t)(4 * g4) * 128 + c) * 4096;
    const size_t imgStride = (size_t)128 * 4096;

    const int wv = tid >> 6, lane = tid & 63;
    const int r = lane & 15, gq = lane >> 4;

    // ---- prefetch image 0 into registers (issue before any setup math)
    float4 xv[4];
    {
        const float4* xg = (const float4*)(x + img0);
        #pragma unroll
        for (int i = 0; i < 4; ++i) xv[i] = xg[tid + i * 256];
    }

    // ---- interpolate 13 -> 127 taps (align_corners linear)
    if (tid < 127) {
        const float scale = 12.0f / 126.0f;
        float pos = (float)tid * scale;
        int   lo  = (int)pos;
        float fr  = pos - (float)lo;
        int   hi  = (lo + 1 < 12) ? lo + 1 : 12;
        hk[tid] = hwt[c * 13 + lo] * (1.0f - fr) + hwt[c * 13 + hi] * fr;
        wk[tid] = wwt[c * 13 + lo] * (1.0f - fr) + wwt[c * 13 + hi] * fr;
    }
    lds_barrier();

    // ---- build Toeplitz factors (bf16) + s_w  (once per block)
    {
        const int row = tid >> 2;            // 0..63
        const int cb  = (tid & 3) * 16;      // col block
        #pragma unroll
        for (int q = 0; q < 4; ++q) {
            us4 vh, vw;
            #pragma unroll
            for (int j = 0; j < 4; ++j) {
                int col = cb + q * 4 + j;                 // = ih (or iw)
                vh[j] = f2bf(hk[col - row + 63]);
                vw[j] = f2bf(wk[col - row + 63]);
            }
            *(us4*)&Ah[row * STRB + cb + q * 4] = vh;
            *(us4*)&Aw[row * STRB + cb + q * 4] = vw;
        }
    }
    if (tid < 64) {
        float s = 0.f;
        #pragma unroll 8
        for (int iw = 0; iw < 64; ++iw) s += wk[iw - tid + 63];
        sw[tid] = s;
    }
    // ---- stage image 0 into Xs
    #pragma unroll
    for (int i = 0; i < 4; ++i) {
        int idx = tid + i * 256;
        int row = idx >> 4;
        int col = (idx & 15) * 4;
        us4 v;
        v[0] = f2bf(xv[i].x); v[1] = f2bf(xv[i].y);
        v[2] = f2bf(xv[i].z); v[3] = f2bf(xv[i].w);
        *(us4*)&Xs[row * STRB + col] = v;
    }
    lds_barrier();

    const float hbc = hb[c], wbc = wb[c];
    float bias_nt[4];
    #pragma unroll
    for (int nt = 0; nt < 4; ++nt) bias_nt[nt] = hbc * sw[nt * 16 + r] + wbc;

    float4 xn[4];

    #pragma unroll
    for (int i = 0; i < 4; ++i) {
        // prefetch next image (registers; latency hides under pass A + pass B)
        if (i < 3) {
            const float4* xg = (const float4*)(x + img0 + (size_t)(i + 1) * imgStride);
            #pragma unroll
            for (int q = 0; q < 4; ++q) xn[q] = xg[tid + q * 256];
        }

        // ---- pass A: P = X * Aw^T ; wave wv owns output rows wv*16..+15
        f32x4 acc[4] = {};
        {
            bfrag a0 = *(const bfrag*)&Xs[(wv * 16 + r) * STRB + gq * 8];
            bfrag a1 = *(const bfrag*)&Xs[(wv * 16 + r) * STRB + 32 + gq * 8];
            #pragma unroll
            for (int nt = 0; nt < 4; ++nt) {
                bfrag b0 = *(const bfrag*)&Aw[(nt * 16 + r) * STRB + gq * 8];
                bfrag b1 = *(const bfrag*)&Aw[(nt * 16 + r) * STRB + 32 + gq * 8];
                acc[nt] = __builtin_amdgcn_mfma_f32_16x16x32_bf16(a0, b0, acc[nt], 0, 0, 0);
                acc[nt] = __builtin_amdgcn_mfma_f32_16x16x32_bf16(a1, b1, acc[nt], 0, 0, 0);
            }
        }
        // epilogue: write P transposed: D[row=16wv+4gq+j][col=nt*16+r] -> PT[col][row]
        #pragma unroll
        for (int nt = 0; nt < 4; ++nt) {
            us4 p;
            p[0] = f2bf(acc[nt][0]); p[1] = f2bf(acc[nt][1]);
            p[2] = f2bf(acc[nt][2]); p[3] = f2bf(acc[nt][3]);
            *(us4*)&PT[(nt * 16 + r) * STRB + wv * 16 + gq * 4] = p;
        }
        lds_barrier();   // PT visible; all pass-A Xs reads done -> Xs free

        // ---- pass B: Z = A_h * P + bias
        f32x4 acc2[4];
        #pragma unroll
        for (int nt = 0; nt < 4; ++nt) {
            float bv = bias_nt[nt];
            acc2[nt] = (f32x4){bv, bv, bv, bv};
        }
        {
            bfrag a0 = *(const bfrag*)&Ah[(wv * 16 + r) * STRB + gq * 8];
            bfrag a1 = *(const bfrag*)&Ah[(wv * 16 + r) * STRB + 32 + gq * 8];
            #pragma unroll
            for (int nt = 0; nt < 4; ++nt) {
                bfrag b0 = *(const bfrag*)&PT[(nt * 16 + r) * STRB + gq * 8];
                bfrag b1 = *(const bfrag*)&PT[(nt * 16 + r) * STRB + 32 + gq * 8];
                acc2[nt] = __builtin_amdgcn_mfma_f32_16x16x32_bf16(a0, b0, acc2[nt], 0, 0, 0);
                acc2[nt] = __builtin_amdgcn_mfma_f32_16x16x32_bf16(a1, b1, acc2[nt], 0, 0, 0);
            }
        }

        // ---- stage next image into Xs (safe: pass-A reads done; pass B ignores Xs)
        if (i < 3) {
            #pragma unroll
            for (int q = 0; q < 4; ++q) {
                int idx = tid + q * 256;
                int row = idx >> 4;
                int col = (idx & 15) * 4;
                us4 v;
                v[0] = f2bf(xn[q].x); v[1] = f2bf(xn[q].y);
                v[2] = f2bf(xn[q].z); v[3] = f2bf(xn[q].w);
                *(us4*)&Xs[row * STRB + col] = v;
            }
        }

        // ---- store Z[i]: D[row=16wv+4gq+j][col=nt*16+r]
        {
            float* og = out + img0 + (size_t)i * imgStride;
            #pragma unroll
            for (int nt = 0; nt < 4; ++nt) {
                #pragma unroll
                for (int j = 0; j < 4; ++j)
                    og[(size_t)(wv * 16 + gq * 4 + j) * 64 + nt * 16 + r] = acc2[nt][j];
            }
        }

        lds_barrier();   // Xs[i+1] visible; all PT reads done -> PT free
    }
}

extern "C" void kernel_launch(void* const* d_in, const int* in_sizes, int n_in,
                              void* d_out, int out_size, void* d_ws, size_t ws_size,
                              hipStream_t stream)
{
    const float* x   = (const float*)d_in[0];
    const float* hwt = (const float*)d_in[1];
    const float* wwt = (const float*)d_in[2];
    const float* hb  = (const float*)d_in[3];
    const float* wb  = (const float*)d_in[4];
    oversize_conv_mfma4<<<1024, 256, 0, stream>>>(x, hwt, wwt, hb, wb, (float*)d_out);
}